// Round 17
// baseline (267.487 us; speedup 1.0000x reference)
//
#include <hip/hip_runtime.h>
#include <hip/hip_bf16.h>
#include <stdint.h>

typedef __hip_bfloat16 bf16;
typedef __attribute__((ext_vector_type(8))) short short8;   // 8 bf16 (4 VGPRs)
typedef __attribute__((ext_vector_type(4))) float floatx4;  // 4 fp32 acc

#define Bb 4
#define Nn 4096
#define Ww 1024
#define Hh 16
#define Aa 64
#define Pp 64
#define Jj 64   // scan chunks per (b,h)
#define Ll 64   // chunk length

__device__ __forceinline__ float clamp20(float z){ return fminf(fmaxf(z, -20.0f), 20.0f); }
__device__ __forceinline__ float b2f(unsigned short u){ return __uint_as_float((unsigned)u << 16); }
__device__ __forceinline__ unsigned short f2b(float f){
    bf16 t = __float2bfloat16(f);
    return *reinterpret_cast<unsigned short*>(&t);
}

__device__ __forceinline__ void gl_lds16(const bf16* g, bf16* l){
    __builtin_amdgcn_global_load_lds((const __attribute__((address_space(1))) void*)g,
                                     (__attribute__((address_space(3))) void*)l, 16, 0, 0);
}

// ===== prep kernels =======================================================
// [R14: prep_x deleted; x-cvt fused into proj_gemm.]

// prep_w: VWt LDS-tile transpose [0,256) | OWt vec [256,1280) | Ktp [1280,1344)
__global__ __launch_bounds__(256) void prep_w(
    const float* __restrict__ k1, const float* __restrict__ k2, const float* __restrict__ k3,
    const float* __restrict__ vw, const float* __restrict__ ow,
    bf16* __restrict__ Ktp, bf16* __restrict__ VWt, bf16* __restrict__ OWt){
    const int blk = blockIdx.x, tid = threadIdx.x;
    if (blk < 256){
        // VWt[(h*64+a)*1024 + w] = vw[h][w][a]; tile (h, w0): 64w x 64a
        __shared__ float tile[64][65];
        const int h = blk >> 4, w0 = (blk & 15) * 64;
#pragma unroll
        for (int p = 0; p < 4; ++p){
            int wr = p * 16 + (tid >> 4);
            int a4 = (tid & 15) * 4;
            float4 v = *(const float4*)(vw + (h << 16) + ((w0 + wr) << 6) + a4);
            tile[wr][a4 + 0] = v.x; tile[wr][a4 + 1] = v.y;
            tile[wr][a4 + 2] = v.z; tile[wr][a4 + 3] = v.w;
        }
        __syncthreads();
#pragma unroll
        for (int p = 0; p < 4; ++p){
            int ar = p * 16 + (tid >> 4);
            int w4 = (tid & 15) * 4;
            ushort4 o = make_ushort4(f2b(tile[w4 + 0][ar]), f2b(tile[w4 + 1][ar]),
                                     f2b(tile[w4 + 2][ar]), f2b(tile[w4 + 3][ar]));
            *(ushort4*)(VWt + (size_t)(h * 64 + ar) * 1024 + w0 + w4) = o;
        }
    } else if (blk < 1280){
        int idx = (blk - 256) * 256 + tid;            // [0, 256K)
        int base = idx * 4;
        int w = base >> 10, r0 = base & 1023;
        int h = r0 >> 6, a0 = r0 & 63;
        float4 v = *(const float4*)(ow + (h << 16) + (w << 6) + a0);
        *(ushort4*)(OWt + base) = make_ushort4(f2b(v.x), f2b(v.y), f2b(v.z), f2b(v.w));
    } else {
        int idx = (blk - 1280) * 256 + tid;           // [0, 16K)
        int base = idx * 4;
        int r = base >> 10, k = base & 1023;
        float4 v = make_float4(0.f, 0.f, 0.f, 0.f);
        if (r < 16)      v = *(const float4*)(k1 + r * 1024 + k);
        else if (r < 32) v = *(const float4*)(k2 + (r - 16) * 1024 + k);
        else if (r < 48) v = *(const float4*)(k3 + (r - 32) * 1024 + k);
        *(ushort4*)(Ktp + base) = make_ushort4(f2b(v.x), f2b(v.y), f2b(v.z), f2b(v.w));
    }
}

// prep_sin: p1/p2e tables; coeffs staged in LDS once per block.
__global__ __launch_bounds__(256) void prep_sin(
    const float* __restrict__ a1, const float* __restrict__ a2,
    const float* __restrict__ b1, const float* __restrict__ b2,
    const float* __restrict__ c,
    float* __restrict__ p1, float* __restrict__ p2e){
    __shared__ float sa1[64], sa2[64], sb1[64], sb2[64], scf[64];
    const int blk = blockIdx.x, tid = threadIdx.x;
    const int h = blk >> 4;                           // 16 blocks per h
    if (tid < 64){
        sa1[tid] = a1[h * 64 + tid];
        sa2[tid] = a2[h * 64 + tid];
        sb1[tid] = b1[h * 64 + tid];
        sb2[tid] = b2[h * 64 + tid];
        scf[tid] = c [h * 64 + tid];
    }
    __syncthreads();
    const int idx = blk * 256 + tid;                  // h*N + i
    const int i = idx & (Nn - 1);
    float t = (float)i * (1.0f / (float)(Nn - 1));
    float s1 = 0.f, s2 = 0.f;
#pragma unroll 8
    for (int p = 0; p < Pp; ++p){
        float cv = scf[p];
        s1 += __sinf(sa1[p] * t + sb1[p]) * cv;
        s2 += __sinf(sa2[p] * t + sb2[p]) * cv;
    }
    p1[idx]  = s1;
    p2e[idx] = expf(clamp20(s2));
}

// ---- projection GEMM + x-cvt fusion, R16 pipelined -----------------------
// [R15: sync-staged version hit 47us (serial chain, vmcnt(0) drains).]
// Double-buffered As/Bs, raw s_barrier, counted vmcnt(2):
//   per iter t: wait X(t)+B(t) (2 newest X-prefetches stay in flight);
//   cvt+ds_write A(t)+store xb; lgkmcnt(0); barrier;
//   post-barrier: gl_lds B(t+1) [safe: all waves past MFMA(t-1)],
//                 issue X(t+2)->regs (static rotation va/vb/nv);
//   MFMA(t).
// vm issue order/iter: store(t), B(t+1), X(t+2)x2 -> entry wait vmcnt(2)
// covers B(t)+X(t) exactly; t==0 and t==nt-1 use vmcnt(0).
__global__ __launch_bounds__(256) void proj_gemm(const float* __restrict__ X,
                                                 const bf16* __restrict__ Ktp,
                                                 const float* __restrict__ p1,
                                                 bf16* __restrict__ xb,
                                                 float* __restrict__ cross_e,
                                                 float* __restrict__ diag_e,
                                                 float* __restrict__ extra_e){
    __shared__ bf16 As[2][64 * 32];
    __shared__ bf16 Bs[2][64 * 32];
    const int tid  = threadIdx.x;
    const int wave = tid >> 6, lane = tid & 63;
    const int m0 = blockIdx.x * 64;

    const int lrow = lane >> 2;            // 0..15
    const int scol = (lane & 3) * 8;       // 0,8,16,24
    const int srow = wave * 16 + lrow;     // 0..63
    const float* Xg = X + (size_t)(m0 + srow) * 1024 + scol;
    const bf16*  Bg = Ktp + (size_t)srow * 1024 + scol;
    bf16* xbg = xb + (size_t)(m0 + srow) * 1024 + scol;
    const int aoff = (wave * 16 + lrow) * 32 + (lane & 3) * 8;   // thread's 16B slot
    const int boff = (wave * 16) * 32;

    floatx4 acc[3] = {};
    const int fr = lane & 15;
    const int fk = (lane >> 4) * 8;
    const int nt = 32;

    // prologue: X(0), X(1) reg loads; B(0) gl_lds
    float4 va0 = *(const float4*)(Xg + 0);
    float4 va1 = *(const float4*)(Xg + 4);
    float4 vb0 = *(const float4*)(Xg + 32);
    float4 vb1 = *(const float4*)(Xg + 36);
    gl_lds16(Bg + 0, &Bs[0][boff]);

    for (int t = 0; t < nt; ++t){
        const int k0 = t * 32;
        if (t == 0 || t == nt - 1) asm volatile("s_waitcnt vmcnt(0)" ::: "memory");
        else                       asm volatile("s_waitcnt vmcnt(2)" ::: "memory");
        __builtin_amdgcn_sched_barrier(0);

        union { ushort4 u4[2]; short8 s8; } pk;
        pk.u4[0] = make_ushort4(f2b(va0.x), f2b(va0.y), f2b(va0.z), f2b(va0.w));
        pk.u4[1] = make_ushort4(f2b(va1.x), f2b(va1.y), f2b(va1.z), f2b(va1.w));
        *(short8*)&As[t & 1][aoff] = pk.s8;    // LDS A slot (16B)
        *(short8*)(xbg + k0) = pk.s8;          // xb byproduct (16B, vmem store)

        asm volatile("s_waitcnt lgkmcnt(0)" ::: "memory");
        __builtin_amdgcn_sched_barrier(0);
        __builtin_amdgcn_s_barrier();          // A(t) visible; all waves past MFMA(t-1)
        __builtin_amdgcn_sched_barrier(0);

        if (t + 1 < nt)
            gl_lds16(Bg + k0 + 32, &Bs[(t + 1) & 1][boff]);
        float4 nv0, nv1;
        const bool pf = (t + 2 < nt);
        if (pf){
            nv0 = *(const float4*)(Xg + k0 + 64);
            nv1 = *(const float4*)(Xg + k0 + 68);
        }
        __builtin_amdgcn_sched_barrier(0);     // pin vm issue order (B then X before reads)

        short8 af = *(const short8*)&As[t & 1][(wave * 16 + fr) * 32 + fk];
        short8 bfr[3];
#pragma unroll
        for (int j = 0; j < 3; ++j)
            bfr[j] = *(const short8*)&Bs[t & 1][(j * 16 + fr) * 32 + fk];
#pragma unroll
        for (int j = 0; j < 3; ++j)
            acc[j] = __builtin_amdgcn_mfma_f32_16x16x32_bf16(af, bfr[j], acc[j], 0, 0, 0);

        va0 = vb0; va1 = vb1;                  // static rotation (no dyn indexing)
        if (pf){ vb0 = nv0; vb1 = nv1; }
    }

    const int cr = (lane >> 4) * 4;
#pragma unroll
    for (int j = 0; j < 3; ++j){
        float* dst = (j == 0) ? cross_e : (j == 1) ? diag_e : extra_e;
#pragma unroll
        for (int r = 0; r < 4; ++r){
            int row = m0 + wave * 16 + cr + r;
            int n = row & (Nn - 1), b = row >> 12;
            float s = acc[j][r];
            if (j == 0) s += p1[fr * Nn + n];
            dst[(b * Hh + fr) * Nn + n] = expf(clamp20(s));
        }
    }
}

// stage one 64-row quarter: 512 threads x 16B. src row-major stride K.
// LDS dest linear (row-major 64x64); global col pre-swizzled (chunk ^ row&7).
__device__ __forceinline__ void stage_q(const bf16* srcTileBase, int K, bf16* ldsQuarter, int tid){
    int r  = tid >> 3;                       // row in quarter 0..63 (r&7 == tile-row&7)
    int col = (((tid & 7) ^ (r & 7)) << 3);  // swizzled source column
    gl_lds16(srcTileBase + (size_t)r * K + col, ldsQuarter + (tid >> 6) * 512);
}

// ---- 256x256 8-wave MFMA GEMM, 4-phase K-schedule, counted vmcnt(6) ------
// [R11: 52.5 -> 46.1us. R14 barrier trim 9->3/K-tile: -> ~42.3us, Mfma 28-30%]
template<int WRITE_BF16>
__global__ __launch_bounds__(512) void gemm256(const bf16* __restrict__ A,
                                               const bf16* __restrict__ Bt,
                                               void* __restrict__ Cv,
                                               int M, int N, int K){
    __shared__ bf16 ldsA[2][256 * 64];
    __shared__ bf16 ldsB[2][256 * 64];
    const int tid  = threadIdx.x;
    const int wave = tid >> 6, lane = tid & 63;

    const int flat = blockIdx.y * gridDim.x + blockIdx.x;
    const int nwg  = gridDim.x * gridDim.y;
    const int cpx  = nwg >> 3;
    const int swz  = (flat & 7) * cpx + (flat >> 3);
    const int m0 = (swz / gridDim.x) * 256, n0 = (swz % gridDim.x) * 256;
    const int wm = (wave >> 2) * 128, wn = (wave & 3) * 64;
    const int fr = lane & 15, quad = lane >> 4;
    const int nt = K >> 6;

    floatx4 acc[8][4] = {};

    // ---- prologue: tile0 all 8 rounds, then tile1's B0-3 + A0,A2 (6) ----
#pragma unroll
    for (int q = 0; q < 4; ++q)
        stage_q(A  + (size_t)(m0 + q * 64) * K, K, &ldsA[0][q * 4096], tid);
#pragma unroll
    for (int q = 0; q < 4; ++q)
        stage_q(Bt + (size_t)(n0 + q * 64) * K, K, &ldsB[0][q * 4096], tid);
#pragma unroll
    for (int q = 0; q < 4; ++q)
        stage_q(Bt + (size_t)(n0 + q * 64) * K + 64, K, &ldsB[1][q * 4096], tid);
    stage_q(A + (size_t)(m0 +   0) * K + 64, K, &ldsA[1][0 * 4096], tid);
    stage_q(A + (size_t)(m0 + 128) * K + 64, K, &ldsA[1][2 * 4096], tid);

    for (int t = 0; t < nt; ++t){
        if (t == nt - 1) asm volatile("s_waitcnt vmcnt(0)" ::: "memory");
        else             asm volatile("s_waitcnt vmcnt(6)" ::: "memory");
        __builtin_amdgcn_sched_barrier(0);
        __builtin_amdgcn_s_barrier();                 // B1: tile-t LDS data complete
        __builtin_amdgcn_sched_barrier(0);

        const bf16* Abuf = ldsA[t & 1];
        const bf16* Bbuf = ldsB[t & 1];
        short8 bfr[4][2];

#pragma unroll
        for (int p = 0; p < 4; ++p){
            short8 af[2][2];
#pragma unroll
            for (int ii = 0; ii < 2; ++ii){
                int R = wm + (2 * p + ii) * 16 + fr;
#pragma unroll
                for (int kc = 0; kc < 2; ++kc){
                    int lb = kc * 4 + quad;
                    af[ii][kc] = *(const short8*)&Abuf[R * 64 + ((lb ^ (R & 7)) << 3)];
                }
            }
            if (p == 0){
#pragma unroll
                for (int j = 0; j < 4; ++j){
                    int R = wn + j * 16 + fr;
#pragma unroll
                    for (int kc = 0; kc < 2; ++kc){
                        int lb = kc * 4 + quad;
                        bfr[j][kc] = *(const short8*)&Bbuf[R * 64 + ((lb ^ (R & 7)) << 3)];
                    }
                }
            }
            // trailing stage issues (uniform guards; 2 gl_lds per phase)
            if (p == 0 && t + 1 < nt){
                bf16* d = ldsA[(t + 1) & 1];
                stage_q(A + (size_t)(m0 +  64) * K + (size_t)(t + 1) * 64, K, d + 1 * 4096, tid);
                stage_q(A + (size_t)(m0 + 192) * K + (size_t)(t + 1) * 64, K, d + 3 * 4096, tid);
            }
            if (p == 1 && t + 2 < nt){
                bf16* d = ldsB[t & 1];
                stage_q(Bt + (size_t)(n0 +   0) * K + (size_t)(t + 2) * 64, K, d + 0 * 4096, tid);
                stage_q(Bt + (size_t)(n0 +  64) * K + (size_t)(t + 2) * 64, K, d + 1 * 4096, tid);
            }
            if (p == 2 && t + 2 < nt){
                bf16* d = ldsB[t & 1];
                stage_q(Bt + (size_t)(n0 + 128) * K + (size_t)(t + 2) * 64, K, d + 2 * 4096, tid);
                stage_q(Bt + (size_t)(n0 + 192) * K + (size_t)(t + 2) * 64, K, d + 3 * 4096, tid);
            }
            if (p == 3 && t + 2 < nt){
                bf16* d = ldsA[t & 1];
                stage_q(A + (size_t)(m0 +   0) * K + (size_t)(t + 2) * 64, K, d + 0 * 4096, tid);
                stage_q(A + (size_t)(m0 + 128) * K + (size_t)(t + 2) * 64, K, d + 2 * 4096, tid);
            }
            __builtin_amdgcn_s_setprio(1);
#pragma unroll
            for (int ii = 0; ii < 2; ++ii)
#pragma unroll
                for (int j = 0; j < 4; ++j)
#pragma unroll
                    for (int kc = 0; kc < 2; ++kc)
                        acc[2 * p + ii][j] = __builtin_amdgcn_mfma_f32_16x16x32_bf16(
                            af[ii][kc], bfr[j][kc], acc[2 * p + ii][j], 0, 0, 0);
            __builtin_amdgcn_s_setprio(0);
            if (p == 0 || p == 1){
                __builtin_amdgcn_s_barrier();         // close@p0 / close@p1 (hazard-required)
                __builtin_amdgcn_sched_barrier(0);
            }
        }
    }

    const int cr = quad * 4;
#pragma unroll
    for (int i = 0; i < 8; ++i)
#pragma unroll
        for (int j = 0; j < 4; ++j){
            int row = m0 + wm + i * 16 + cr;
            int col = n0 + wn + j * 16 + fr;
            if (WRITE_BF16){
                bf16* C = (bf16*)Cv;
#pragma unroll
                for (int r = 0; r < 4; ++r)
                    C[(size_t)(row + r) * N + col] = __float2bfloat16(acc[i][j][r]);
            } else {
                float* C = (float*)Cv;
#pragma unroll
                for (int r = 0; r < 4; ++r)
                    C[(size_t)(row + r) * N + col] = acc[i][j][r];
            }
        }
}

// ---- scan pass 1: per-chunk sums (vectorized: ushort4 = 8B/lane) ---------
__global__ __launch_bounds__(64) void scan1(const bf16* __restrict__ values,
                                            const float* __restrict__ cross_e,
                                            float* __restrict__ csum_c, float* __restrict__ csum_cv){
    const int blk = blockIdx.x;          // (b*H + h)*J + j
    const int j = blk & (Jj - 1);
    const int bh = blk >> 6;
    const int h = bh & (Hh - 1), b = bh >> 4;
    const int lane = threadIdx.x;
    const int tq = lane >> 4;            // 0..3
    const int a4 = (lane & 15) << 2;     // a base (x4)
    const float* cp = cross_e + bh * Nn + j * Ll;
    float sc = 0.f, s0 = 0.f, s1 = 0.f, s2 = 0.f, s3 = 0.f;
#pragma unroll
    for (int i = 0; i < 16; ++i){
        int t = tq * 16 + i;
        int n = j * Ll + t;
        float ce = cp[t];
        ushort4 pv = *(const ushort4*)(values + (((size_t)(b * Nn + n)) << 10) + (h << 6) + a4);
        sc += ce;
        s0 += ce * b2f(pv.x); s1 += ce * b2f(pv.y);
        s2 += ce * b2f(pv.z); s3 += ce * b2f(pv.w);
    }
    sc += __shfl_xor(sc, 16); sc += __shfl_xor(sc, 32);
    s0 += __shfl_xor(s0, 16); s0 += __shfl_xor(s0, 32);
    s1 += __shfl_xor(s1, 16); s1 += __shfl_xor(s1, 32);
    s2 += __shfl_xor(s2, 16); s2 += __shfl_xor(s2, 32);
    s3 += __shfl_xor(s3, 16); s3 += __shfl_xor(s3, 32);
    if (lane == 0) csum_c[blk] = sc;
    if (tq == 0){
        float4 o = make_float4(s0, s1, s2, s3);
        *(float4*)(csum_cv + (blk << 6) + a4) = o;
    }
}

// ---- scan pass 2: exclusive prefix over chunks ---------------------------
__global__ __launch_bounds__(64) void scan2(const float* __restrict__ csum_c,
                                            const float* __restrict__ csum_cv,
                                            float* __restrict__ pref_c, float* __restrict__ pref_cv){
    const int bh = blockIdx.x;
    const int lane = threadIdx.x;
    float rc = 0.f, rcv = 0.f;
    for (int j = 0; j < Jj; ++j){
        int idx = bh * Jj + j;
        if (lane == 0) pref_c[idx] = rc;
        pref_cv[(idx << 6) + lane] = rcv;
        rc  += csum_c[idx];
        rcv += csum_cv[(idx << 6) + lane];
    }
}

// ---- scan pass 3: apply + pointwise -> out2 bf16 [B][N][H*A] -------------
__global__ __launch_bounds__(64) void scan3(const bf16* __restrict__ values,
                                            const float* __restrict__ cross_e,
                                            const float* __restrict__ diag_e,
                                            const float* __restrict__ extra_e,
                                            const float* __restrict__ p2e,
                                            const float* __restrict__ pref_c,
                                            const float* __restrict__ pref_cv,
                                            bf16* __restrict__ out2){
    const int blk = blockIdx.x;
    const int j = blk & (Jj - 1);
    const int bh = blk >> 6;
    const int h = bh & (Hh - 1), b = bh >> 4;
    const int lane = threadIdx.x;
    const int tq = lane >> 4;            // 0..3
    const int al = lane & 15;
    const int a4 = al << 2;
    const float* cp = cross_e + bh * Nn + j * Ll;
    const float* dp = diag_e  + bh * Nn + j * Ll;
    const float* ep = extra_e + bh * Nn + j * Ll;
    const float* pp = p2e + h * Nn + j * Ll;

    ushort4 pv[16];
    float cef[16];
    float lc = 0.f, l0 = 0.f, l1 = 0.f, l2 = 0.f, l3 = 0.f;
#pragma unroll
    for (int i = 0; i < 16; ++i){
        int t = tq * 16 + i;
        int n = j * Ll + t;
        cef[i] = cp[t];
        pv[i] = *(const ushort4*)(values + (((size_t)(b * Nn + n)) << 10) + (h << 6) + a4);
        float ce = cef[i];
        lc += ce;
        l0 += ce * b2f(pv[i].x); l1 += ce * b2f(pv[i].y);
        l2 += ce * b2f(pv[i].z); l3 += ce * b2f(pv[i].w);
    }

    float rc = pref_c[blk];
    float4 pcv = *(const float4*)(pref_cv + (blk << 6) + a4);
    float r0 = pcv.x, r1 = pcv.y, r2 = pcv.z, r3 = pcv.w;
#pragma unroll
    for (int g = 0; g < 3; ++g){
        int src = g * 16 + al;
        float oc = __shfl(lc, src);
        float o0 = __shfl(l0, src), o1 = __shfl(l1, src);
        float o2 = __shfl(l2, src), o3 = __shfl(l3, src);
        if (tq > g){ rc += oc; r0 += o0; r1 += o1; r2 += o2; r3 += o3; }
    }

#pragma unroll
    for (int i = 0; i < 16; ++i){
        int t = tq * 16 + i;
        int n = j * Ll + t;
        float ce = cef[i], de = dp[t], ee = ep[t], pe = pp[t];
        float v0 = b2f(pv[i].x), v1 = b2f(pv[i].y);
        float v2 = b2f(pv[i].z), v3 = b2f(pv[i].w);
        rc += ce;
        r0 += ce * v0; r1 += ce * v1; r2 += ce * v2; r3 += ce * v3;
        float pee = pe * ee;
        float invd = 1.0f / (rc * pee + de);   // den is a-independent
        ushort4 o;
        o.x = f2b((r0 * pee + v0 * de) * invd);
        o.y = f2b((r1 * pee + v1 * de) * invd);
        o.z = f2b((r2 * pee + v2 * de) * invd);
        o.w = f2b((r3 * pee + v3 * de) * invd);
        *(ushort4*)(out2 + (((size_t)(b * Nn + n)) << 10) + (h << 6) + a4) = o;
    }
}

extern "C" void kernel_launch(void* const* d_in, const int* in_sizes, int n_in,
                              void* d_out, int out_size, void* d_ws, size_t ws_size,
                              hipStream_t stream){
    const float* x  = (const float*)d_in[0];
    const float* k1 = (const float*)d_in[1];
    const float* k2 = (const float*)d_in[2];
    const float* k3 = (const float*)d_in[3];
    const float* a1 = (const float*)d_in[4];
    const float* a2 = (const float*)d_in[5];
    const float* b1 = (const float*)d_in[6];
    const float* b2 = (const float*)d_in[7];
    const float* c  = (const float*)d_in[8];
    const float* vw = (const float*)d_in[9];
    const float* ow = (const float*)d_in[10];
    float* out = (float*)d_out;

    char* p = (char*)d_ws;
    auto alloc = [&](size_t bytes) -> void* {
        void* r = (void*)p;
        p += (bytes + 255) & ~(size_t)255;
        return r;
    };
    bf16*  xb      = (bf16*) alloc((size_t)Bb * Nn * Ww * 2);
    bf16*  Ktp     = (bf16*) alloc((size_t)64 * Ww * 2);
    bf16*  VWt     = (bf16*) alloc((size_t)Hh * Aa * Ww * 2);
    bf16*  OWt     = (bf16*) alloc((size_t)Ww * Hh * Aa * 2);
    float* p1      = (float*)alloc((size_t)Hh * Nn * 4);
    float* p2e     = (float*)alloc((size_t)Hh * Nn * 4);
    float* cross_e = (float*)alloc((size_t)Bb * Hh * Nn * 4);
    float* diag_e  = (float*)alloc((size_t)Bb * Hh * Nn * 4);
    float* extra_e = (float*)alloc((size_t)Bb * Hh * Nn * 4);
    float* csum_c  = (float*)alloc((size_t)Bb * Hh * Jj * 4);
    float* pref_c  = (float*)alloc((size_t)Bb * Hh * Jj * 4);
    float* csum_cv = (float*)alloc((size_t)Bb * Hh * Jj * Aa * 4);
    float* pref_cv = (float*)alloc((size_t)Bb * Hh * Jj * Aa * 4);
    bf16*  values  = (bf16*) alloc((size_t)Bb * Nn * Hh * Aa * 2);
    bf16*  out2    = (bf16*) alloc((size_t)Bb * Nn * Hh * Aa * 2);

    prep_w  <<<1344, 256, 0, stream>>>(k1, k2, k3, vw, ow, Ktp, VWt, OWt);
    prep_sin<<<256, 256, 0, stream>>>(a1, a2, b1, b2, c, p1, p2e);
    proj_gemm<<<(Bb * Nn) / 64, 256, 0, stream>>>(x, Ktp, p1, xb, cross_e, diag_e, extra_e);
    gemm256<1><<<dim3((Hh * Aa) / 256, (Bb * Nn) / 256), 512, 0, stream>>>(xb, VWt, (void*)values, Bb * Nn, Hh * Aa, Ww);
    scan1<<<Bb * Hh * Jj, 64, 0, stream>>>(values, cross_e, csum_c, csum_cv);
    scan2<<<Bb * Hh, 64, 0, stream>>>(csum_c, csum_cv, pref_c, pref_cv);
    scan3<<<Bb * Hh * Jj, 64, 0, stream>>>(values, cross_e, diag_e, extra_e, p2e, pref_c, pref_cv, out2);
    gemm256<0><<<dim3(Ww / 256, (Bb * Nn) / 256), 512, 0, stream>>>(out2, OWt, (void*)out, Bb * Nn, Ww, Hh * Aa);
}

// Round 18
// 257.664 us; speedup vs baseline: 1.0381x; 1.0381x over previous
//
#include <hip/hip_runtime.h>
#include <hip/hip_bf16.h>
#include <stdint.h>

typedef __hip_bfloat16 bf16;
typedef __attribute__((ext_vector_type(8))) short short8;   // 8 bf16 (4 VGPRs)
typedef __attribute__((ext_vector_type(4))) float floatx4;  // 4 fp32 acc

#define Bb 4
#define Nn 4096
#define Ww 1024
#define Hh 16
#define Aa 64
#define Pp 64
#define Jj 64   // scan chunks per (b,h)
#define Ll 64   // chunk length

__device__ __forceinline__ float clamp20(float z){ return fminf(fmaxf(z, -20.0f), 20.0f); }
__device__ __forceinline__ float b2f(unsigned short u){ return __uint_as_float((unsigned)u << 16); }
__device__ __forceinline__ unsigned short f2b(float f){
    bf16 t = __float2bfloat16(f);
    return *reinterpret_cast<unsigned short*>(&t);
}

__device__ __forceinline__ void gl_lds16(const bf16* g, bf16* l){
    __builtin_amdgcn_global_load_lds((const __attribute__((address_space(1))) void*)g,
                                     (__attribute__((address_space(3))) void*)l, 16, 0, 0);
}

// ===== prep kernels =======================================================

// prep_w: VWt LDS-tile transpose [0,256) | OWt vec [256,1280) | Ktp [1280,1344)
__global__ __launch_bounds__(256) void prep_w(
    const float* __restrict__ k1, const float* __restrict__ k2, const float* __restrict__ k3,
    const float* __restrict__ vw, const float* __restrict__ ow,
    bf16* __restrict__ Ktp, bf16* __restrict__ VWt, bf16* __restrict__ OWt){
    const int blk = blockIdx.x, tid = threadIdx.x;
    if (blk < 256){
        // VWt[(h*64+a)*1024 + w] = vw[h][w][a]; tile (h, w0): 64w x 64a
        __shared__ float tile[64][65];
        const int h = blk >> 4, w0 = (blk & 15) * 64;
#pragma unroll
        for (int p = 0; p < 4; ++p){
            int wr = p * 16 + (tid >> 4);
            int a4 = (tid & 15) * 4;
            float4 v = *(const float4*)(vw + (h << 16) + ((w0 + wr) << 6) + a4);
            tile[wr][a4 + 0] = v.x; tile[wr][a4 + 1] = v.y;
            tile[wr][a4 + 2] = v.z; tile[wr][a4 + 3] = v.w;
        }
        __syncthreads();
#pragma unroll
        for (int p = 0; p < 4; ++p){
            int ar = p * 16 + (tid >> 4);
            int w4 = (tid & 15) * 4;
            ushort4 o = make_ushort4(f2b(tile[w4 + 0][ar]), f2b(tile[w4 + 1][ar]),
                                     f2b(tile[w4 + 2][ar]), f2b(tile[w4 + 3][ar]));
            *(ushort4*)(VWt + (size_t)(h * 64 + ar) * 1024 + w0 + w4) = o;
        }
    } else if (blk < 1280){
        int idx = (blk - 256) * 256 + tid;            // [0, 256K)
        int base = idx * 4;
        int w = base >> 10, r0 = base & 1023;
        int h = r0 >> 6, a0 = r0 & 63;
        float4 v = *(const float4*)(ow + (h << 16) + (w << 6) + a0);
        *(ushort4*)(OWt + base) = make_ushort4(f2b(v.x), f2b(v.y), f2b(v.z), f2b(v.w));
    } else {
        int idx = (blk - 1280) * 256 + tid;           // [0, 16K)
        int base = idx * 4;
        int r = base >> 10, k = base & 1023;
        float4 v = make_float4(0.f, 0.f, 0.f, 0.f);
        if (r < 16)      v = *(const float4*)(k1 + r * 1024 + k);
        else if (r < 32) v = *(const float4*)(k2 + (r - 16) * 1024 + k);
        else if (r < 48) v = *(const float4*)(k3 + (r - 32) * 1024 + k);
        *(ushort4*)(Ktp + base) = make_ushort4(f2b(v.x), f2b(v.y), f2b(v.z), f2b(v.w));
    }
}

// prep_sin: p1/p2e tables; coeffs staged in LDS once per block.
__global__ __launch_bounds__(256) void prep_sin(
    const float* __restrict__ a1, const float* __restrict__ a2,
    const float* __restrict__ b1, const float* __restrict__ b2,
    const float* __restrict__ c,
    float* __restrict__ p1, float* __restrict__ p2e){
    __shared__ float sa1[64], sa2[64], sb1[64], sb2[64], scf[64];
    const int blk = blockIdx.x, tid = threadIdx.x;
    const int h = blk >> 4;                           // 16 blocks per h
    if (tid < 64){
        sa1[tid] = a1[h * 64 + tid];
        sa2[tid] = a2[h * 64 + tid];
        sb1[tid] = b1[h * 64 + tid];
        sb2[tid] = b2[h * 64 + tid];
        scf[tid] = c [h * 64 + tid];
    }
    __syncthreads();
    const int idx = blk * 256 + tid;                  // h*N + i
    const int i = idx & (Nn - 1);
    float t = (float)i * (1.0f / (float)(Nn - 1));
    float s1 = 0.f, s2 = 0.f;
#pragma unroll 8
    for (int p = 0; p < Pp; ++p){
        float cv = scf[p];
        s1 += __sinf(sa1[p] * t + sb1[p]) * cv;
        s2 += __sinf(sa2[p] * t + sb2[p]) * cv;
    }
    p1[idx]  = s1;
    p2e[idx] = expf(clamp20(s2));
}

// ---- projection GEMM + x-cvt fusion, R18: BK=128, nt=8, A direct-to-reg --
// [R15 sync 47us, R16 pipelined 47us -> per-iter ~1.5us invariant across
//  structures; lever = fewer serial iterations + no A-LDS round trip.]
// Each lane loads ITS OWN A-fragment of X (row wave*16+fr, cols kk+quad*8),
// cvt in-reg -> afr + xb byproduct. B (Ktp) gl_lds-staged, dbuf, XOR-swz.
// Per iter: vmcnt(15) [keep stores(t-1)+X(t+1)+B(t+1) in flight] -> pack/
// store -> bar#1 (B(t) all-waves) -> bfr reads+lgkm(0) -> bar#2 -> prefetch
// X(t+2)/B(t+2) -> 12 MFMA.
__global__ __launch_bounds__(256) void proj_gemm(const float* __restrict__ X,
                                                 const bf16* __restrict__ Ktp,
                                                 const float* __restrict__ p1,
                                                 bf16* __restrict__ xb,
                                                 float* __restrict__ cross_e,
                                                 float* __restrict__ diag_e,
                                                 float* __restrict__ extra_e){
    __shared__ bf16 Bs[2][48 * 128];
    const int tid  = threadIdx.x;
    const int wave = tid >> 6, lane = tid & 63;
    const int m0 = blockIdx.x * 64;
    const int fr = lane & 15, quad = lane >> 4;

    const float* Xf = X  + (size_t)(m0 + wave * 16 + fr) * 1024 + quad * 8;
    bf16*       xbf = xb + (size_t)(m0 + wave * 16 + fr) * 1024 + quad * 8;

    floatx4 acc[3] = {};
    float4 xA[8], xB[8];

    auto loadX = [&](float4 (&d)[8], int t){
#pragma unroll
        for (int i = 0; i < 4; ++i){
            d[2 * i]     = *(const float4*)(Xf + t * 128 + 32 * i);
            d[2 * i + 1] = *(const float4*)(Xf + t * 128 + 32 * i + 4);
        }
    };
    auto stageB = [&](int t){
        bf16* base = &Bs[t & 1][0];
#pragma unroll
        for (int s = 0; s < 3; ++s){
            int c = tid + s * 256;
            int row = c >> 4, pch = c & 15;
            int gcol = (pch ^ (row & 7)) << 3;
            gl_lds16(Ktp + (size_t)row * 1024 + t * 128 + gcol,
                     base + (size_t)(wave * 64 + s * 256) * 8);   // wave-uniform LDS base
        }
    };
    auto iter = [&](int t, float4 (&xc_)[8], int vmN){
        if (vmN == 0)       asm volatile("s_waitcnt vmcnt(0)"  ::: "memory");
        else if (vmN == 11) asm volatile("s_waitcnt vmcnt(11)" ::: "memory");
        else                asm volatile("s_waitcnt vmcnt(15)" ::: "memory");
        __builtin_amdgcn_sched_barrier(0);
        // pack A fragments + xb byproduct stores
        short8 afr[4];
#pragma unroll
        for (int i = 0; i < 4; ++i){
            union { ushort4 u4[2]; short8 s8; } pk;
            pk.u4[0] = make_ushort4(f2b(xc_[2*i].x),   f2b(xc_[2*i].y),
                                    f2b(xc_[2*i].z),   f2b(xc_[2*i].w));
            pk.u4[1] = make_ushort4(f2b(xc_[2*i+1].x), f2b(xc_[2*i+1].y),
                                    f2b(xc_[2*i+1].z), f2b(xc_[2*i+1].w));
            afr[i] = pk.s8;
            *(short8*)(xbf + t * 128 + i * 32) = pk.s8;
        }
        __builtin_amdgcn_sched_barrier(0);
        __builtin_amdgcn_s_barrier();                 // #1: all waves' B(t) in LDS
        __builtin_amdgcn_sched_barrier(0);
        short8 bfr[3][4];
#pragma unroll
        for (int j = 0; j < 3; ++j)
#pragma unroll
            for (int i = 0; i < 4; ++i){
                int R = j * 16 + fr;
                int pch = (4 * i + quad) ^ (R & 7);
                bfr[j][i] = *(const short8*)&Bs[t & 1][R * 128 + pch * 8];
            }
        asm volatile("s_waitcnt lgkmcnt(0)" ::: "memory");
        __builtin_amdgcn_sched_barrier(0);
        __builtin_amdgcn_s_barrier();                 // #2: all waves done reading Bs[t&1]
        __builtin_amdgcn_sched_barrier(0);
        if (t + 2 < 8){ loadX(xc_, t + 2); stageB(t + 2); }
        __builtin_amdgcn_sched_barrier(0);
#pragma unroll
        for (int i = 0; i < 4; ++i)
#pragma unroll
            for (int j = 0; j < 3; ++j)
                acc[j] = __builtin_amdgcn_mfma_f32_16x16x32_bf16(afr[i], bfr[j][i], acc[j], 0, 0, 0);
    };

    // prologue: X(0),B(0),X(1),B(1)  (22 vm ops; entry t=0 keeps last 11)
    loadX(xA, 0); stageB(0);
    loadX(xB, 1); stageB(1);
    __builtin_amdgcn_sched_barrier(0);

#pragma unroll
    for (int tt = 0; tt < 4; ++tt){
        iter(2 * tt,     xA, (tt == 0) ? 11 : 15);
        iter(2 * tt + 1, xB, (tt == 3) ? 0  : 15);
    }

    const int cr = quad * 4;
#pragma unroll
    for (int j = 0; j < 3; ++j){
        float* dst = (j == 0) ? cross_e : (j == 1) ? diag_e : extra_e;
#pragma unroll
        for (int r = 0; r < 4; ++r){
            int row = m0 + wave * 16 + cr + r;
            int n = row & (Nn - 1), b = row >> 12;
            float s = acc[j][r];
            if (j == 0) s += p1[fr * Nn + n];
            dst[(b * Hh + fr) * Nn + n] = expf(clamp20(s));
        }
    }
}

// stage one 64-row quarter: 512 threads x 16B. src row-major stride K.
// LDS dest linear (row-major 64x64); global col pre-swizzled (chunk ^ row&7).
__device__ __forceinline__ void stage_q(const bf16* srcTileBase, int K, bf16* ldsQuarter, int tid){
    int r  = tid >> 3;                       // row in quarter 0..63 (r&7 == tile-row&7)
    int col = (((tid & 7) ^ (r & 7)) << 3);  // swizzled source column
    gl_lds16(srcTileBase + (size_t)r * K + col, ldsQuarter + (tid >> 6) * 512);
}

// ---- 256x256 8-wave MFMA GEMM, 4-phase K-schedule, counted vmcnt(6) ------
// [R11: 52.5 -> 46.1us. R14 barrier trim 9->3/K-tile: -> ~42.3us, Mfma 28-30%]
template<int WRITE_BF16>
__global__ __launch_bounds__(512) void gemm256(const bf16* __restrict__ A,
                                               const bf16* __restrict__ Bt,
                                               void* __restrict__ Cv,
                                               int M, int N, int K){
    __shared__ bf16 ldsA[2][256 * 64];
    __shared__ bf16 ldsB[2][256 * 64];
    const int tid  = threadIdx.x;
    const int wave = tid >> 6, lane = tid & 63;

    const int flat = blockIdx.y * gridDim.x + blockIdx.x;
    const int nwg  = gridDim.x * gridDim.y;
    const int cpx  = nwg >> 3;
    const int swz  = (flat & 7) * cpx + (flat >> 3);
    const int m0 = (swz / gridDim.x) * 256, n0 = (swz % gridDim.x) * 256;
    const int wm = (wave >> 2) * 128, wn = (wave & 3) * 64;
    const int fr = lane & 15, quad = lane >> 4;
    const int nt = K >> 6;

    floatx4 acc[8][4] = {};

    // ---- prologue: tile0 all 8 rounds, then tile1's B0-3 + A0,A2 (6) ----
#pragma unroll
    for (int q = 0; q < 4; ++q)
        stage_q(A  + (size_t)(m0 + q * 64) * K, K, &ldsA[0][q * 4096], tid);
#pragma unroll
    for (int q = 0; q < 4; ++q)
        stage_q(Bt + (size_t)(n0 + q * 64) * K, K, &ldsB[0][q * 4096], tid);
#pragma unroll
    for (int q = 0; q < 4; ++q)
        stage_q(Bt + (size_t)(n0 + q * 64) * K + 64, K, &ldsB[1][q * 4096], tid);
    stage_q(A + (size_t)(m0 +   0) * K + 64, K, &ldsA[1][0 * 4096], tid);
    stage_q(A + (size_t)(m0 + 128) * K + 64, K, &ldsA[1][2 * 4096], tid);

    for (int t = 0; t < nt; ++t){
        if (t == nt - 1) asm volatile("s_waitcnt vmcnt(0)" ::: "memory");
        else             asm volatile("s_waitcnt vmcnt(6)" ::: "memory");
        __builtin_amdgcn_sched_barrier(0);
        __builtin_amdgcn_s_barrier();                 // B1: tile-t LDS data complete
        __builtin_amdgcn_sched_barrier(0);

        const bf16* Abuf = ldsA[t & 1];
        const bf16* Bbuf = ldsB[t & 1];
        short8 bfr[4][2];

#pragma unroll
        for (int p = 0; p < 4; ++p){
            short8 af[2][2];
#pragma unroll
            for (int ii = 0; ii < 2; ++ii){
                int R = wm + (2 * p + ii) * 16 + fr;
#pragma unroll
                for (int kc = 0; kc < 2; ++kc){
                    int lb = kc * 4 + quad;
                    af[ii][kc] = *(const short8*)&Abuf[R * 64 + ((lb ^ (R & 7)) << 3)];
                }
            }
            if (p == 0){
#pragma unroll
                for (int j = 0; j < 4; ++j){
                    int R = wn + j * 16 + fr;
#pragma unroll
                    for (int kc = 0; kc < 2; ++kc){
                        int lb = kc * 4 + quad;
                        bfr[j][kc] = *(const short8*)&Bbuf[R * 64 + ((lb ^ (R & 7)) << 3)];
                    }
                }
            }
            // trailing stage issues (uniform guards; 2 gl_lds per phase)
            if (p == 0 && t + 1 < nt){
                bf16* d = ldsA[(t + 1) & 1];
                stage_q(A + (size_t)(m0 +  64) * K + (size_t)(t + 1) * 64, K, d + 1 * 4096, tid);
                stage_q(A + (size_t)(m0 + 192) * K + (size_t)(t + 1) * 64, K, d + 3 * 4096, tid);
            }
            if (p == 1 && t + 2 < nt){
                bf16* d = ldsB[t & 1];
                stage_q(Bt + (size_t)(n0 +   0) * K + (size_t)(t + 2) * 64, K, d + 0 * 4096, tid);
                stage_q(Bt + (size_t)(n0 +  64) * K + (size_t)(t + 2) * 64, K, d + 1 * 4096, tid);
            }
            if (p == 2 && t + 2 < nt){
                bf16* d = ldsB[t & 1];
                stage_q(Bt + (size_t)(n0 + 128) * K + (size_t)(t + 2) * 64, K, d + 2 * 4096, tid);
                stage_q(Bt + (size_t)(n0 + 192) * K + (size_t)(t + 2) * 64, K, d + 3 * 4096, tid);
            }
            if (p == 3 && t + 2 < nt){
                bf16* d = ldsA[t & 1];
                stage_q(A + (size_t)(m0 +   0) * K + (size_t)(t + 2) * 64, K, d + 0 * 4096, tid);
                stage_q(A + (size_t)(m0 + 128) * K + (size_t)(t + 2) * 64, K, d + 2 * 4096, tid);
            }
            __builtin_amdgcn_s_setprio(1);
#pragma unroll
            for (int ii = 0; ii < 2; ++ii)
#pragma unroll
                for (int j = 0; j < 4; ++j)
#pragma unroll
                    for (int kc = 0; kc < 2; ++kc)
                        acc[2 * p + ii][j] = __builtin_amdgcn_mfma_f32_16x16x32_bf16(
                            af[ii][kc], bfr[j][kc], acc[2 * p + ii][j], 0, 0, 0);
            __builtin_amdgcn_s_setprio(0);
            if (p == 0 || p == 1){
                __builtin_amdgcn_s_barrier();         // close@p0 / close@p1 (hazard-required)
                __builtin_amdgcn_sched_barrier(0);
            }
        }
    }

    const int cr = quad * 4;
#pragma unroll
    for (int i = 0; i < 8; ++i)
#pragma unroll
        for (int j = 0; j < 4; ++j){
            int row = m0 + wm + i * 16 + cr;
            int col = n0 + wn + j * 16 + fr;
            if (WRITE_BF16){
                bf16* C = (bf16*)Cv;
#pragma unroll
                for (int r = 0; r < 4; ++r)
                    C[(size_t)(row + r) * N + col] = __float2bfloat16(acc[i][j][r]);
            } else {
                float* C = (float*)Cv;
#pragma unroll
                for (int r = 0; r < 4; ++r)
                    C[(size_t)(row + r) * N + col] = acc[i][j][r];
            }
        }
}

// ---- scan pass 1: per-chunk sums (vectorized: ushort4 = 8B/lane) ---------
__global__ __launch_bounds__(64) void scan1(const bf16* __restrict__ values,
                                            const float* __restrict__ cross_e,
                                            float* __restrict__ csum_c, float* __restrict__ csum_cv){
    const int blk = blockIdx.x;          // (b*H + h)*J + j
    const int j = blk & (Jj - 1);
    const int bh = blk >> 6;
    const int h = bh & (Hh - 1), b = bh >> 4;
    const int lane = threadIdx.x;
    const int tq = lane >> 4;            // 0..3
    const int a4 = (lane & 15) << 2;     // a base (x4)
    const float* cp = cross_e + bh * Nn + j * Ll;
    float sc = 0.f, s0 = 0.f, s1 = 0.f, s2 = 0.f, s3 = 0.f;
#pragma unroll
    for (int i = 0; i < 16; ++i){
        int t = tq * 16 + i;
        int n = j * Ll + t;
        float ce = cp[t];
        ushort4 pv = *(const ushort4*)(values + (((size_t)(b * Nn + n)) << 10) + (h << 6) + a4);
        sc += ce;
        s0 += ce * b2f(pv.x); s1 += ce * b2f(pv.y);
        s2 += ce * b2f(pv.z); s3 += ce * b2f(pv.w);
    }
    sc += __shfl_xor(sc, 16); sc += __shfl_xor(sc, 32);
    s0 += __shfl_xor(s0, 16); s0 += __shfl_xor(s0, 32);
    s1 += __shfl_xor(s1, 16); s1 += __shfl_xor(s1, 32);
    s2 += __shfl_xor(s2, 16); s2 += __shfl_xor(s2, 32);
    s3 += __shfl_xor(s3, 16); s3 += __shfl_xor(s3, 32);
    if (lane == 0) csum_c[blk] = sc;
    if (tq == 0){
        float4 o = make_float4(s0, s1, s2, s3);
        *(float4*)(csum_cv + (blk << 6) + a4) = o;
    }
}

// ---- scan pass 2: exclusive prefix over chunks ---------------------------
__global__ __launch_bounds__(64) void scan2(const float* __restrict__ csum_c,
                                            const float* __restrict__ csum_cv,
                                            float* __restrict__ pref_c, float* __restrict__ pref_cv){
    const int bh = blockIdx.x;
    const int lane = threadIdx.x;
    float rc = 0.f, rcv = 0.f;
    for (int j = 0; j < Jj; ++j){
        int idx = bh * Jj + j;
        if (lane == 0) pref_c[idx] = rc;
        pref_cv[(idx << 6) + lane] = rcv;
        rc  += csum_c[idx];
        rcv += csum_cv[(idx << 6) + lane];
    }
}

// ---- scan pass 3: apply + pointwise -> out2 bf16 [B][N][H*A] -------------
__global__ __launch_bounds__(64) void scan3(const bf16* __restrict__ values,
                                            const float* __restrict__ cross_e,
                                            const float* __restrict__ diag_e,
                                            const float* __restrict__ extra_e,
                                            const float* __restrict__ p2e,
                                            const float* __restrict__ pref_c,
                                            const float* __restrict__ pref_cv,
                                            bf16* __restrict__ out2){
    const int blk = blockIdx.x;
    const int j = blk & (Jj - 1);
    const int bh = blk >> 6;
    const int h = bh & (Hh - 1), b = bh >> 4;
    const int lane = threadIdx.x;
    const int tq = lane >> 4;            // 0..3
    const int al = lane & 15;
    const int a4 = al << 2;
    const float* cp = cross_e + bh * Nn + j * Ll;
    const float* dp = diag_e  + bh * Nn + j * Ll;
    const float* ep = extra_e + bh * Nn + j * Ll;
    const float* pp = p2e + h * Nn + j * Ll;

    ushort4 pv[16];
    float cef[16];
    float lc = 0.f, l0 = 0.f, l1 = 0.f, l2 = 0.f, l3 = 0.f;
#pragma unroll
    for (int i = 0; i < 16; ++i){
        int t = tq * 16 + i;
        int n = j * Ll + t;
        cef[i] = cp[t];
        pv[i] = *(const ushort4*)(values + (((size_t)(b * Nn + n)) << 10) + (h << 6) + a4);
        float ce = cef[i];
        lc += ce;
        l0 += ce * b2f(pv[i].x); l1 += ce * b2f(pv[i].y);
        l2 += ce * b2f(pv[i].z); l3 += ce * b2f(pv[i].w);
    }

    float rc = pref_c[blk];
    float4 pcv = *(const float4*)(pref_cv + (blk << 6) + a4);
    float r0 = pcv.x, r1 = pcv.y, r2 = pcv.z, r3 = pcv.w;
#pragma unroll
    for (int g = 0; g < 3; ++g){
        int src = g * 16 + al;
        float oc = __shfl(lc, src);
        float o0 = __shfl(l0, src), o1 = __shfl(l1, src);
        float o2 = __shfl(l2, src), o3 = __shfl(l3, src);
        if (tq > g){ rc += oc; r0 += o0; r1 += o1; r2 += o2; r3 += o3; }
    }

#pragma unroll
    for (int i = 0; i < 16; ++i){
        int t = tq * 16 + i;
        int n = j * Ll + t;
        float ce = cef[i], de = dp[t], ee = ep[t], pe = pp[t];
        float v0 = b2f(pv[i].x), v1 = b2f(pv[i].y);
        float v2 = b2f(pv[i].z), v3 = b2f(pv[i].w);
        rc += ce;
        r0 += ce * v0; r1 += ce * v1; r2 += ce * v2; r3 += ce * v3;
        float pee = pe * ee;
        float invd = 1.0f / (rc * pee + de);   // den is a-independent
        ushort4 o;
        o.x = f2b((r0 * pee + v0 * de) * invd);
        o.y = f2b((r1 * pee + v1 * de) * invd);
        o.z = f2b((r2 * pee + v2 * de) * invd);
        o.w = f2b((r3 * pee + v3 * de) * invd);
        *(ushort4*)(out2 + (((size_t)(b * Nn + n)) << 10) + (h << 6) + a4) = o;
    }
}

extern "C" void kernel_launch(void* const* d_in, const int* in_sizes, int n_in,
                              void* d_out, int out_size, void* d_ws, size_t ws_size,
                              hipStream_t stream){
    const float* x  = (const float*)d_in[0];
    const float* k1 = (const float*)d_in[1];
    const float* k2 = (const float*)d_in[2];
    const float* k3 = (const float*)d_in[3];
    const float* a1 = (const float*)d_in[4];
    const float* a2 = (const float*)d_in[5];
    const float* b1 = (const float*)d_in[6];
    const float* b2 = (const float*)d_in[7];
    const float* c  = (const float*)d_in[8];
    const float* vw = (const float*)d_in[9];
    const float* ow = (const float*)d_in[10];
    float* out = (float*)d_out;

    char* p = (char*)d_ws;
    auto alloc = [&](size_t bytes) -> void* {
        void* r = (void*)p;
        p += (bytes + 255) & ~(size_t)255;
        return r;
    };
    bf16*  xb      = (bf16*) alloc((size_t)Bb * Nn * Ww * 2);
    bf16*  Ktp     = (bf16*) alloc((size_t)64 * Ww * 2);
    bf16*  VWt     = (bf16*) alloc((size_t)Hh * Aa * Ww * 2);
    bf16*  OWt     = (bf16*) alloc((size_t)Ww * Hh * Aa * 2);
    float* p1      = (float*)alloc((size_t)Hh * Nn * 4);
    float* p2e     = (float*)alloc((size_t)Hh * Nn * 4);
    float* cross_e = (float*)alloc((size_t)Bb * Hh * Nn * 4);
    float* diag_e  = (float*)alloc((size_t)Bb * Hh * Nn * 4);
    float* extra_e = (float*)alloc((size_t)Bb * Hh * Nn * 4);
    float* csum_c  = (float*)alloc((size_t)Bb * Hh * Jj * 4);
    float* pref_c  = (float*)alloc((size_t)Bb * Hh * Jj * 4);
    float* csum_cv = (float*)alloc((size_t)Bb * Hh * Jj * Aa * 4);
    float* pref_cv = (float*)alloc((size_t)Bb * Hh * Jj * Aa * 4);
    bf16*  values  = (bf16*) alloc((size_t)Bb * Nn * Hh * Aa * 2);
    bf16*  out2    = (bf16*) alloc((size_t)Bb * Nn * Hh * Aa * 2);

    prep_w  <<<1344, 256, 0, stream>>>(k1, k2, k3, vw, ow, Ktp, VWt, OWt);
    prep_sin<<<256, 256, 0, stream>>>(a1, a2, b1, b2, c, p1, p2e);
    proj_gemm<<<(Bb * Nn) / 64, 256, 0, stream>>>(x, Ktp, p1, xb, cross_e, diag_e, extra_e);
    gemm256<1><<<dim3((Hh * Aa) / 256, (Bb * Nn) / 256), 512, 0, stream>>>(xb, VWt, (void*)values, Bb * Nn, Hh * Aa, Ww);
    scan1<<<Bb * Hh * Jj, 64, 0, stream>>>(values, cross_e, csum_c, csum_cv);
    scan2<<<Bb * Hh, 64, 0, stream>>>(csum_c, csum_cv, pref_c, pref_cv);
    scan3<<<Bb * Hh * Jj, 64, 0, stream>>>(values, cross_e, diag_e, extra_e, p2e, pref_c, pref_cv, out2);
    gemm256<0><<<dim3(Ww / 256, (Bb * Nn) / 256), 512, 0, stream>>>(out2, OWt, (void*)out, Bb * Nn, Ww, Hh * Aa);
}

// Round 19
// 255.706 us; speedup vs baseline: 1.0461x; 1.0077x over previous
//
#include <hip/hip_runtime.h>
#include <hip/hip_bf16.h>
#include <stdint.h>

typedef __hip_bfloat16 bf16;
typedef __attribute__((ext_vector_type(8))) short short8;   // 8 bf16 (4 VGPRs)
typedef __attribute__((ext_vector_type(4))) float floatx4;  // 4 fp32 acc

#define Bb 4
#define Nn 4096
#define Ww 1024
#define Hh 16
#define Aa 64
#define Pp 64
#define Jj 64   // scan chunks per (b,h)
#define Ll 64   // chunk length

__device__ __forceinline__ float clamp20(float z){ return fminf(fmaxf(z, -20.0f), 20.0f); }
__device__ __forceinline__ float b2f(unsigned short u){ return __uint_as_float((unsigned)u << 16); }
__device__ __forceinline__ unsigned short f2b(float f){
    bf16 t = __float2bfloat16(f);
    return *reinterpret_cast<unsigned short*>(&t);
}

__device__ __forceinline__ void gl_lds16(const bf16* g, bf16* l){
    __builtin_amdgcn_global_load_lds((const __attribute__((address_space(1))) void*)g,
                                     (__attribute__((address_space(3))) void*)l, 16, 0, 0);
}

// ===== prep kernels =======================================================

// prep_w: VWt LDS-tile transpose [0,256) | OWt vec [256,1280) | Ktp [1280,1344)
__global__ __launch_bounds__(256) void prep_w(
    const float* __restrict__ k1, const float* __restrict__ k2, const float* __restrict__ k3,
    const float* __restrict__ vw, const float* __restrict__ ow,
    bf16* __restrict__ Ktp, bf16* __restrict__ VWt, bf16* __restrict__ OWt){
    const int blk = blockIdx.x, tid = threadIdx.x;
    if (blk < 256){
        // VWt[(h*64+a)*1024 + w] = vw[h][w][a]; tile (h, w0): 64w x 64a
        __shared__ float tile[64][65];
        const int h = blk >> 4, w0 = (blk & 15) * 64;
#pragma unroll
        for (int p = 0; p < 4; ++p){
            int wr = p * 16 + (tid >> 4);
            int a4 = (tid & 15) * 4;
            float4 v = *(const float4*)(vw + (h << 16) + ((w0 + wr) << 6) + a4);
            tile[wr][a4 + 0] = v.x; tile[wr][a4 + 1] = v.y;
            tile[wr][a4 + 2] = v.z; tile[wr][a4 + 3] = v.w;
        }
        __syncthreads();
#pragma unroll
        for (int p = 0; p < 4; ++p){
            int ar = p * 16 + (tid >> 4);
            int w4 = (tid & 15) * 4;
            ushort4 o = make_ushort4(f2b(tile[w4 + 0][ar]), f2b(tile[w4 + 1][ar]),
                                     f2b(tile[w4 + 2][ar]), f2b(tile[w4 + 3][ar]));
            *(ushort4*)(VWt + (size_t)(h * 64 + ar) * 1024 + w0 + w4) = o;
        }
    } else if (blk < 1280){
        int idx = (blk - 256) * 256 + tid;            // [0, 256K)
        int base = idx * 4;
        int w = base >> 10, r0 = base & 1023;
        int h = r0 >> 6, a0 = r0 & 63;
        float4 v = *(const float4*)(ow + (h << 16) + (w << 6) + a0);
        *(ushort4*)(OWt + base) = make_ushort4(f2b(v.x), f2b(v.y), f2b(v.z), f2b(v.w));
    } else {
        int idx = (blk - 1280) * 256 + tid;           // [0, 16K)
        int base = idx * 4;
        int r = base >> 10, k = base & 1023;
        float4 v = make_float4(0.f, 0.f, 0.f, 0.f);
        if (r < 16)      v = *(const float4*)(k1 + r * 1024 + k);
        else if (r < 32) v = *(const float4*)(k2 + (r - 16) * 1024 + k);
        else if (r < 48) v = *(const float4*)(k3 + (r - 32) * 1024 + k);
        *(ushort4*)(Ktp + base) = make_ushort4(f2b(v.x), f2b(v.y), f2b(v.z), f2b(v.w));
    }
}

// prep_sin: p1/p2e tables; coeffs staged in LDS once per block.
__global__ __launch_bounds__(256) void prep_sin(
    const float* __restrict__ a1, const float* __restrict__ a2,
    const float* __restrict__ b1, const float* __restrict__ b2,
    const float* __restrict__ c,
    float* __restrict__ p1, float* __restrict__ p2e){
    __shared__ float sa1[64], sa2[64], sb1[64], sb2[64], scf[64];
    const int blk = blockIdx.x, tid = threadIdx.x;
    const int h = blk >> 4;                           // 16 blocks per h
    if (tid < 64){
        sa1[tid] = a1[h * 64 + tid];
        sa2[tid] = a2[h * 64 + tid];
        sb1[tid] = b1[h * 64 + tid];
        sb2[tid] = b2[h * 64 + tid];
        scf[tid] = c [h * 64 + tid];
    }
    __syncthreads();
    const int idx = blk * 256 + tid;                  // h*N + i
    const int i = idx & (Nn - 1);
    float t = (float)i * (1.0f / (float)(Nn - 1));
    float s1 = 0.f, s2 = 0.f;
#pragma unroll 8
    for (int p = 0; p < Pp; ++p){
        float cv = scf[p];
        s1 += __sinf(sa1[p] * t + sb1[p]) * cv;
        s2 += __sinf(sa2[p] * t + sb2[p]) * cv;
    }
    p1[idx]  = s1;
    p2e[idx] = expf(clamp20(s2));
}

// ---- projection GEMM + x-cvt fusion (R18 structure, kept) ----------------
// [~44us is a positional tax (poison-drain): invariant across 4 rewrites.]
__global__ __launch_bounds__(256) void proj_gemm(const float* __restrict__ X,
                                                 const bf16* __restrict__ Ktp,
                                                 const float* __restrict__ p1,
                                                 bf16* __restrict__ xb,
                                                 float* __restrict__ cross_e,
                                                 float* __restrict__ diag_e,
                                                 float* __restrict__ extra_e){
    __shared__ bf16 Bs[2][48 * 128];
    const int tid  = threadIdx.x;
    const int wave = tid >> 6, lane = tid & 63;
    const int m0 = blockIdx.x * 64;
    const int fr = lane & 15, quad = lane >> 4;

    const float* Xf = X  + (size_t)(m0 + wave * 16 + fr) * 1024 + quad * 8;
    bf16*       xbf = xb + (size_t)(m0 + wave * 16 + fr) * 1024 + quad * 8;

    floatx4 acc[3] = {};
    float4 xA[8], xB[8];

    auto loadX = [&](float4 (&d)[8], int t){
#pragma unroll
        for (int i = 0; i < 4; ++i){
            d[2 * i]     = *(const float4*)(Xf + t * 128 + 32 * i);
            d[2 * i + 1] = *(const float4*)(Xf + t * 128 + 32 * i + 4);
        }
    };
    auto stageB = [&](int t){
        bf16* base = &Bs[t & 1][0];
#pragma unroll
        for (int s = 0; s < 3; ++s){
            int c = tid + s * 256;
            int row = c >> 4, pch = c & 15;
            int gcol = (pch ^ (row & 7)) << 3;
            gl_lds16(Ktp + (size_t)row * 1024 + t * 128 + gcol,
                     base + (size_t)(wave * 64 + s * 256) * 8);   // wave-uniform LDS base
        }
    };
    auto iter = [&](int t, float4 (&xc_)[8], int vmN){
        if (vmN == 0)       asm volatile("s_waitcnt vmcnt(0)"  ::: "memory");
        else if (vmN == 11) asm volatile("s_waitcnt vmcnt(11)" ::: "memory");
        else                asm volatile("s_waitcnt vmcnt(15)" ::: "memory");
        __builtin_amdgcn_sched_barrier(0);
        // pack A fragments + xb byproduct stores
        short8 afr[4];
#pragma unroll
        for (int i = 0; i < 4; ++i){
            union { ushort4 u4[2]; short8 s8; } pk;
            pk.u4[0] = make_ushort4(f2b(xc_[2*i].x),   f2b(xc_[2*i].y),
                                    f2b(xc_[2*i].z),   f2b(xc_[2*i].w));
            pk.u4[1] = make_ushort4(f2b(xc_[2*i+1].x), f2b(xc_[2*i+1].y),
                                    f2b(xc_[2*i+1].z), f2b(xc_[2*i+1].w));
            afr[i] = pk.s8;
            *(short8*)(xbf + t * 128 + i * 32) = pk.s8;
        }
        __builtin_amdgcn_sched_barrier(0);
        __builtin_amdgcn_s_barrier();                 // #1: all waves' B(t) in LDS
        __builtin_amdgcn_sched_barrier(0);
        short8 bfr[3][4];
#pragma unroll
        for (int j = 0; j < 3; ++j)
#pragma unroll
            for (int i = 0; i < 4; ++i){
                int R = j * 16 + fr;
                int pch = (4 * i + quad) ^ (R & 7);
                bfr[j][i] = *(const short8*)&Bs[t & 1][R * 128 + pch * 8];
            }
        asm volatile("s_waitcnt lgkmcnt(0)" ::: "memory");
        __builtin_amdgcn_sched_barrier(0);
        __builtin_amdgcn_s_barrier();                 // #2: all waves done reading Bs[t&1]
        __builtin_amdgcn_sched_barrier(0);
        if (t + 2 < 8){ loadX(xc_, t + 2); stageB(t + 2); }
        __builtin_amdgcn_sched_barrier(0);
#pragma unroll
        for (int i = 0; i < 4; ++i)
#pragma unroll
            for (int j = 0; j < 3; ++j)
                acc[j] = __builtin_amdgcn_mfma_f32_16x16x32_bf16(afr[i], bfr[j][i], acc[j], 0, 0, 0);
    };

    // prologue: X(0),B(0),X(1),B(1)  (22 vm ops; entry t=0 keeps last 11)
    loadX(xA, 0); stageB(0);
    loadX(xB, 1); stageB(1);
    __builtin_amdgcn_sched_barrier(0);

#pragma unroll
    for (int tt = 0; tt < 4; ++tt){
        iter(2 * tt,     xA, (tt == 0) ? 11 : 15);
        iter(2 * tt + 1, xB, (tt == 3) ? 0  : 15);
    }

    const int cr = quad * 4;
#pragma unroll
    for (int j = 0; j < 3; ++j){
        float* dst = (j == 0) ? cross_e : (j == 1) ? diag_e : extra_e;
#pragma unroll
        for (int r = 0; r < 4; ++r){
            int row = m0 + wave * 16 + cr + r;
            int n = row & (Nn - 1), b = row >> 12;
            float s = acc[j][r];
            if (j == 0) s += p1[fr * Nn + n];
            dst[(b * Hh + fr) * Nn + n] = expf(clamp20(s));
        }
    }
}

// stage one 64-row quarter: 512 threads x 16B. src row-major stride K.
// LDS dest linear (row-major 64x64); global col pre-swizzled (chunk ^ row&7).
__device__ __forceinline__ void stage_q(const bf16* srcTileBase, int K, bf16* ldsQuarter, int tid){
    int r  = tid >> 3;                       // row in quarter 0..63 (r&7 == tile-row&7)
    int col = (((tid & 7) ^ (r & 7)) << 3);  // swizzled source column
    gl_lds16(srcTileBase + (size_t)r * K + col, ldsQuarter + (tid >> 6) * 512);
}

// ---- 256x256 8-wave MFMA GEMM, 4-phase K-schedule, counted vmcnt(6) ------
// [R11: 52.5->46.1us; R14 barrier trim -> ~42.3-44us, Mfma ~30%.]
// R19: WRITE_BF16==1 instantiation fuses scan1 into the epilogue:
//   stages the block's cross_e tile (4 h x 256 n = 4KB) into LDS, then each
//   wave (one h; a = j*16+fr) computes csum_cv[bh][chunk][a] = sum cross*val
//   via in-lane i,r sums + quad shfl_xor reduce, and csum_c via butterfly.
//   Each (b,h,chunk) is written exactly once (2 wm-waves x 2 chunks x 16
//   row-blocks x 1 wave-per-h = 64 chunks per (b,h)).
template<int WRITE_BF16>
__global__ __launch_bounds__(512) void gemm256(const bf16* __restrict__ A,
                                               const bf16* __restrict__ Bt,
                                               void* __restrict__ Cv,
                                               const float* __restrict__ cross_e,
                                               float* __restrict__ csum_c,
                                               float* __restrict__ csum_cv,
                                               int M, int N, int K){
    __shared__ bf16 ldsA[2][256 * 64];
    __shared__ bf16 ldsB[2][256 * 64];
    const int tid  = threadIdx.x;
    const int wave = tid >> 6, lane = tid & 63;

    const int flat = blockIdx.y * gridDim.x + blockIdx.x;
    const int nwg  = gridDim.x * gridDim.y;
    const int cpx  = nwg >> 3;
    const int swz  = (flat & 7) * cpx + (flat >> 3);
    const int m0 = (swz / gridDim.x) * 256, n0 = (swz % gridDim.x) * 256;
    const int wm = (wave >> 2) * 128, wn = (wave & 3) * 64;
    const int fr = lane & 15, quad = lane >> 4;
    const int nt = K >> 6;

    floatx4 acc[8][4] = {};

    // ---- prologue: tile0 all 8 rounds, then tile1's B0-3 + A0,A2 (6) ----
#pragma unroll
    for (int q = 0; q < 4; ++q)
        stage_q(A  + (size_t)(m0 + q * 64) * K, K, &ldsA[0][q * 4096], tid);
#pragma unroll
    for (int q = 0; q < 4; ++q)
        stage_q(Bt + (size_t)(n0 + q * 64) * K, K, &ldsB[0][q * 4096], tid);
#pragma unroll
    for (int q = 0; q < 4; ++q)
        stage_q(Bt + (size_t)(n0 + q * 64) * K + 64, K, &ldsB[1][q * 4096], tid);
    stage_q(A + (size_t)(m0 +   0) * K + 64, K, &ldsA[1][0 * 4096], tid);
    stage_q(A + (size_t)(m0 + 128) * K + 64, K, &ldsA[1][2 * 4096], tid);

    for (int t = 0; t < nt; ++t){
        if (t == nt - 1) asm volatile("s_waitcnt vmcnt(0)" ::: "memory");
        else             asm volatile("s_waitcnt vmcnt(6)" ::: "memory");
        __builtin_amdgcn_sched_barrier(0);
        __builtin_amdgcn_s_barrier();                 // B1: tile-t LDS data complete
        __builtin_amdgcn_sched_barrier(0);

        const bf16* Abuf = ldsA[t & 1];
        const bf16* Bbuf = ldsB[t & 1];
        short8 bfr[4][2];

#pragma unroll
        for (int p = 0; p < 4; ++p){
            short8 af[2][2];
#pragma unroll
            for (int ii = 0; ii < 2; ++ii){
                int R = wm + (2 * p + ii) * 16 + fr;
#pragma unroll
                for (int kc = 0; kc < 2; ++kc){
                    int lb = kc * 4 + quad;
                    af[ii][kc] = *(const short8*)&Abuf[R * 64 + ((lb ^ (R & 7)) << 3)];
                }
            }
            if (p == 0){
#pragma unroll
                for (int j = 0; j < 4; ++j){
                    int R = wn + j * 16 + fr;
#pragma unroll
                    for (int kc = 0; kc < 2; ++kc){
                        int lb = kc * 4 + quad;
                        bfr[j][kc] = *(const short8*)&Bbuf[R * 64 + ((lb ^ (R & 7)) << 3)];
                    }
                }
            }
            // trailing stage issues (uniform guards; 2 gl_lds per phase)
            if (p == 0 && t + 1 < nt){
                bf16* d = ldsA[(t + 1) & 1];
                stage_q(A + (size_t)(m0 +  64) * K + (size_t)(t + 1) * 64, K, d + 1 * 4096, tid);
                stage_q(A + (size_t)(m0 + 192) * K + (size_t)(t + 1) * 64, K, d + 3 * 4096, tid);
            }
            if (p == 1 && t + 2 < nt){
                bf16* d = ldsB[t & 1];
                stage_q(Bt + (size_t)(n0 +   0) * K + (size_t)(t + 2) * 64, K, d + 0 * 4096, tid);
                stage_q(Bt + (size_t)(n0 +  64) * K + (size_t)(t + 2) * 64, K, d + 1 * 4096, tid);
            }
            if (p == 2 && t + 2 < nt){
                bf16* d = ldsB[t & 1];
                stage_q(Bt + (size_t)(n0 + 128) * K + (size_t)(t + 2) * 64, K, d + 2 * 4096, tid);
                stage_q(Bt + (size_t)(n0 + 192) * K + (size_t)(t + 2) * 64, K, d + 3 * 4096, tid);
            }
            if (p == 3 && t + 2 < nt){
                bf16* d = ldsA[t & 1];
                stage_q(A + (size_t)(m0 +   0) * K + (size_t)(t + 2) * 64, K, d + 0 * 4096, tid);
                stage_q(A + (size_t)(m0 + 128) * K + (size_t)(t + 2) * 64, K, d + 2 * 4096, tid);
            }
            __builtin_amdgcn_s_setprio(1);
#pragma unroll
            for (int ii = 0; ii < 2; ++ii)
#pragma unroll
                for (int j = 0; j < 4; ++j)
#pragma unroll
                    for (int kc = 0; kc < 2; ++kc)
                        acc[2 * p + ii][j] = __builtin_amdgcn_mfma_f32_16x16x32_bf16(
                            af[ii][kc], bfr[j][kc], acc[2 * p + ii][j], 0, 0, 0);
            __builtin_amdgcn_s_setprio(0);
            if (p == 0 || p == 1){
                __builtin_amdgcn_s_barrier();         // close@p0 / close@p1 (hazard-required)
                __builtin_amdgcn_sched_barrier(0);
            }
        }
    }

    const int cr = quad * 4;
#pragma unroll
    for (int i = 0; i < 8; ++i)
#pragma unroll
        for (int j = 0; j < 4; ++j){
            int row = m0 + wm + i * 16 + cr;
            int col = n0 + wn + j * 16 + fr;
            if (WRITE_BF16){
                bf16* C = (bf16*)Cv;
#pragma unroll
                for (int r = 0; r < 4; ++r)
                    C[(size_t)(row + r) * N + col] = __float2bfloat16(acc[i][j][r]);
            } else {
                float* C = (float*)Cv;
#pragma unroll
                for (int r = 0; r < 4; ++r)
                    C[(size_t)(row + r) * N + col] = acc[i][j][r];
            }
        }

    if (WRITE_BF16){
        // ---- fused scan1: chunk sums from live accumulators ----
        __syncthreads();                              // main-loop LDS reads done
        float* crossLds = (float*)&ldsA[0][0];        // 4 h x 256 n = 4KB
        const int b  = m0 >> 12;
        const int nb = m0 & (Nn - 1);
#pragma unroll
        for (int s = 0; s < 2; ++s){
            int idx = tid + s * 512;
            int hh = idx >> 8, nn = idx & 255;
            crossLds[hh * 256 + nn] =
                cross_e[(size_t)((b << 4) + (n0 >> 6) + hh) * Nn + nb + nn];
        }
        __syncthreads();
        const int hl = wn >> 6;                       // wave's h within tile (0..3)
        const int bh = (b << 4) + (n0 >> 6) + hl;
#pragma unroll
        for (int cc = 0; cc < 2; ++cc){
            float sj[4] = {0.f, 0.f, 0.f, 0.f};
#pragma unroll
            for (int i = 0; i < 4; ++i){
                int ii = cc * 4 + i;
#pragma unroll
                for (int r = 0; r < 4; ++r){
                    float cw = crossLds[hl * 256 + wm + ii * 16 + quad * 4 + r];
#pragma unroll
                    for (int j = 0; j < 4; ++j)
                        sj[j] += cw * acc[ii][j][r];
                }
            }
#pragma unroll
            for (int j = 0; j < 4; ++j){
                sj[j] += __shfl_xor(sj[j], 16);
                sj[j] += __shfl_xor(sj[j], 32);
            }
            const int jg = (nb >> 6) + (wm >> 6) + cc;   // global chunk in [0,64)
            if (quad == 0){
#pragma unroll
                for (int j = 0; j < 4; ++j)
                    csum_cv[((size_t)(bh * Jj + jg) << 6) + j * 16 + fr] = sj[j];
            }
            float vc = crossLds[hl * 256 + wm + cc * 64 + lane];
            vc += __shfl_xor(vc, 1);  vc += __shfl_xor(vc, 2);
            vc += __shfl_xor(vc, 4);  vc += __shfl_xor(vc, 8);
            vc += __shfl_xor(vc, 16); vc += __shfl_xor(vc, 32);
            if (lane == 0) csum_c[bh * Jj + jg] = vc;
        }
    }
}

// ---- scan pass 2: exclusive prefix over chunks ---------------------------
__global__ __launch_bounds__(64) void scan2(const float* __restrict__ csum_c,
                                            const float* __restrict__ csum_cv,
                                            float* __restrict__ pref_c, float* __restrict__ pref_cv){
    const int bh = blockIdx.x;
    const int lane = threadIdx.x;
    float rc = 0.f, rcv = 0.f;
    for (int j = 0; j < Jj; ++j){
        int idx = bh * Jj + j;
        if (lane == 0) pref_c[idx] = rc;
        pref_cv[(idx << 6) + lane] = rcv;
        rc  += csum_c[idx];
        rcv += csum_cv[(idx << 6) + lane];
    }
}

// ---- scan pass 3: apply + pointwise -> out2 bf16 [B][N][H*A] -------------
__global__ __launch_bounds__(64) void scan3(const bf16* __restrict__ values,
                                            const float* __restrict__ cross_e,
                                            const float* __restrict__ diag_e,
                                            const float* __restrict__ extra_e,
                                            const float* __restrict__ p2e,
                                            const float* __restrict__ pref_c,
                                            const float* __restrict__ pref_cv,
                                            bf16* __restrict__ out2){
    const int blk = blockIdx.x;
    const int j = blk & (Jj - 1);
    const int bh = blk >> 6;
    const int h = bh & (Hh - 1), b = bh >> 4;
    const int lane = threadIdx.x;
    const int tq = lane >> 4;            // 0..3
    const int al = lane & 15;
    const int a4 = al << 2;
    const float* cp = cross_e + bh * Nn + j * Ll;
    const float* dp = diag_e  + bh * Nn + j * Ll;
    const float* ep = extra_e + bh * Nn + j * Ll;
    const float* pp = p2e + h * Nn + j * Ll;

    ushort4 pv[16];
    float cef[16];
    float lc = 0.f, l0 = 0.f, l1 = 0.f, l2 = 0.f, l3 = 0.f;
#pragma unroll
    for (int i = 0; i < 16; ++i){
        int t = tq * 16 + i;
        int n = j * Ll + t;
        cef[i] = cp[t];
        pv[i] = *(const ushort4*)(values + (((size_t)(b * Nn + n)) << 10) + (h << 6) + a4);
        float ce = cef[i];
        lc += ce;
        l0 += ce * b2f(pv[i].x); l1 += ce * b2f(pv[i].y);
        l2 += ce * b2f(pv[i].z); l3 += ce * b2f(pv[i].w);
    }

    float rc = pref_c[blk];
    float4 pcv = *(const float4*)(pref_cv + (blk << 6) + a4);
    float r0 = pcv.x, r1 = pcv.y, r2 = pcv.z, r3 = pcv.w;
#pragma unroll
    for (int g = 0; g < 3; ++g){
        int src = g * 16 + al;
        float oc = __shfl(lc, src);
        float o0 = __shfl(l0, src), o1 = __shfl(l1, src);
        float o2 = __shfl(l2, src), o3 = __shfl(l3, src);
        if (tq > g){ rc += oc; r0 += o0; r1 += o1; r2 += o2; r3 += o3; }
    }

#pragma unroll
    for (int i = 0; i < 16; ++i){
        int t = tq * 16 + i;
        int n = j * Ll + t;
        float ce = cef[i], de = dp[t], ee = ep[t], pe = pp[t];
        float v0 = b2f(pv[i].x), v1 = b2f(pv[i].y);
        float v2 = b2f(pv[i].z), v3 = b2f(pv[i].w);
        rc += ce;
        r0 += ce * v0; r1 += ce * v1; r2 += ce * v2; r3 += ce * v3;
        float pee = pe * ee;
        float invd = 1.0f / (rc * pee + de);   // den is a-independent
        ushort4 o;
        o.x = f2b((r0 * pee + v0 * de) * invd);
        o.y = f2b((r1 * pee + v1 * de) * invd);
        o.z = f2b((r2 * pee + v2 * de) * invd);
        o.w = f2b((r3 * pee + v3 * de) * invd);
        *(ushort4*)(out2 + (((size_t)(b * Nn + n)) << 10) + (h << 6) + a4) = o;
    }
}

extern "C" void kernel_launch(void* const* d_in, const int* in_sizes, int n_in,
                              void* d_out, int out_size, void* d_ws, size_t ws_size,
                              hipStream_t stream){
    const float* x  = (const float*)d_in[0];
    const float* k1 = (const float*)d_in[1];
    const float* k2 = (const float*)d_in[2];
    const float* k3 = (const float*)d_in[3];
    const float* a1 = (const float*)d_in[4];
    const float* a2 = (const float*)d_in[5];
    const float* b1 = (const float*)d_in[6];
    const float* b2 = (const float*)d_in[7];
    const float* c  = (const float*)d_in[8];
    const float* vw = (const float*)d_in[9];
    const float* ow = (const float*)d_in[10];
    float* out = (float*)d_out;

    char* p = (char*)d_ws;
    auto alloc = [&](size_t bytes) -> void* {
        void* r = (void*)p;
        p += (bytes + 255) & ~(size_t)255;
        return r;
    };
    bf16*  xb      = (bf16*) alloc((size_t)Bb * Nn * Ww * 2);
    bf16*  Ktp     = (bf16*) alloc((size_t)64 * Ww * 2);
    bf16*  VWt     = (bf16*) alloc((size_t)Hh * Aa * Ww * 2);
    bf16*  OWt     = (bf16*) alloc((size_t)Ww * Hh * Aa * 2);
    float* p1      = (float*)alloc((size_t)Hh * Nn * 4);
    float* p2e     = (float*)alloc((size_t)Hh * Nn * 4);
    float* cross_e = (float*)alloc((size_t)Bb * Hh * Nn * 4);
    float* diag_e  = (float*)alloc((size_t)Bb * Hh * Nn * 4);
    float* extra_e = (float*)alloc((size_t)Bb * Hh * Nn * 4);
    float* csum_c  = (float*)alloc((size_t)Bb * Hh * Jj * 4);
    float* pref_c  = (float*)alloc((size_t)Bb * Hh * Jj * 4);
    float* csum_cv = (float*)alloc((size_t)Bb * Hh * Jj * Aa * 4);
    float* pref_cv = (float*)alloc((size_t)Bb * Hh * Jj * Aa * 4);
    bf16*  values  = (bf16*) alloc((size_t)Bb * Nn * Hh * Aa * 2);
    bf16*  out2    = (bf16*) alloc((size_t)Bb * Nn * Hh * Aa * 2);

    prep_w  <<<1344, 256, 0, stream>>>(k1, k2, k3, vw, ow, Ktp, VWt, OWt);
    prep_sin<<<256, 256, 0, stream>>>(a1, a2, b1, b2, c, p1, p2e);
    proj_gemm<<<(Bb * Nn) / 64, 256, 0, stream>>>(x, Ktp, p1, xb, cross_e, diag_e, extra_e);
    gemm256<1><<<dim3((Hh * Aa) / 256, (Bb * Nn) / 256), 512, 0, stream>>>(
        xb, VWt, (void*)values, cross_e, csum_c, csum_cv, Bb * Nn, Hh * Aa, Ww);
    scan2<<<Bb * Hh, 64, 0, stream>>>(csum_c, csum_cv, pref_c, pref_cv);
    scan3<<<Bb * Hh * Jj, 64, 0, stream>>>(values, cross_e, diag_e, extra_e, p2e, pref_c, pref_cv, out2);
    gemm256<0><<<dim3(Ww / 256, (Bb * Nn) / 256), 512, 0, stream>>>(
        out2, OWt, (void*)out, nullptr, nullptr, nullptr, Bb * Nn, Ww, Hh * Aa);
}